// Round 3
// baseline (730.099 us; speedup 1.0000x reference)
//
#include <hip/hip_runtime.h>
#include <hip/hip_bf16.h>
#include <cstdint>
#include <cstddef>

// Problem: RNN-T joint. B=4,T=256,U=64, ENC=DEC=640, INNER=512, VOCAB=2048.
// All inputs fp32 (per reference dtypes); output fp32 (4,256,64,2048).

typedef __attribute__((ext_vector_type(8))) short   short8;   // 8 bf16 (4 VGPRs)
typedef __attribute__((ext_vector_type(4))) float   floatx4;  // MFMA acc

__device__ __forceinline__ short f2bf(float f) {
  union { float f; unsigned u; } v; v.f = f;
  unsigned r = (v.u + 0x7fffu + ((v.u >> 16) & 1u)) >> 16;  // RNE
  return (short)(unsigned short)r;
}

// async global->LDS, 16B per lane (global_load_lds_dwordx4)
__device__ __forceinline__ void async16(const void* g, void* l) {
  __builtin_amdgcn_global_load_lds(
      (const __attribute__((address_space(1))) unsigned int*)g,
      (__attribute__((address_space(3))) unsigned int*)l,
      16, 0, 0);
}

// fp32 -> bf16 bulk convert, 8 elems/thread. n8 = n/8 (all tensors %8==0).
__global__ __launch_bounds__(256)
void f32_to_bf16(const float* __restrict__ in, short* __restrict__ out, int n8)
{
  const int i = blockIdx.x * 256 + threadIdx.x;
  if (i >= n8) return;
  const float4* p = (const float4*)in + 2 * (size_t)i;
  const float4 a = p[0], b = p[1];
  short8 o;
  o[0] = f2bf(a.x); o[1] = f2bf(a.y); o[2] = f2bf(a.z); o[3] = f2bf(a.w);
  o[4] = f2bf(b.x); o[5] = f2bf(b.y); o[6] = f2bf(b.z); o[7] = f2bf(b.w);
  ((short8*)out)[i] = o;
}

// C[m][n] = sum_k A[m][k]*B[n][k] (+ bias[n]); A: MxK bf16 (lda), B: NxK bf16
// (ldb, col offset bcol). 128x128 tile, BK=32, 4 waves 2x2, 4x4 MFMA 16x16x32.
// Output fp32, bias fp32 (nullable). m97-verified structure.
__global__ __launch_bounds__(256)
void gemm_bt(const short* __restrict__ A, int lda,
             const short* __restrict__ B, int ldb, int bcol,
             float* __restrict__ Cout, int ldc,
             const float* __restrict__ bias, int K)
{
  __shared__ short As[128 * 32];  // 8 KiB, [m][k]
  __shared__ short Bs[128 * 32];  // 8 KiB, [n][k]

  const int tid  = threadIdx.x;
  const int lane = tid & 63;
  const int wave = tid >> 6;
  const int wm = (wave >> 1) << 6;
  const int wn = (wave & 1) << 6;
  const int m_base = blockIdx.y * 128;
  const int n_base = blockIdx.x * 128;

  floatx4 acc[4][4];
#pragma unroll
  for (int i = 0; i < 4; i++)
#pragma unroll
    for (int j = 0; j < 4; j++) acc[i][j] = (floatx4)0.0f;

  // staging: thread tid copies 8 elems to LDS flat offset tid*8
  // flat = m*32+k -> m = tid/4, k = (tid&3)*8; second call m += 64
  const short* Ag = A + (size_t)(m_base + (tid >> 2)) * lda + ((tid & 3) * 8);
  const short* Bg = B + (size_t)(n_base + (tid >> 2)) * ldb + bcol + ((tid & 3) * 8);
  short* Al = &As[tid * 8];
  short* Bl = &Bs[tid * 8];
  const size_t aHalf = (size_t)64 * lda;
  const size_t bHalf = (size_t)64 * ldb;

  const int ak   = (lane >> 4) * 8;  // k base of fragment
  const int arow = lane & 15;

  for (int kb = 0; kb < K; kb += 32) {
    __syncthreads();
    async16(Ag + kb,         Al);
    async16(Ag + kb + aHalf, Al + 2048);
    async16(Bg + kb,         Bl);
    async16(Bg + kb + bHalf, Bl + 2048);
    __syncthreads();  // compiler drains vmcnt before barrier

    short8 af[4], bfr[4];
#pragma unroll
    for (int i = 0; i < 4; i++)
      af[i] = *(const short8*)&As[(wm + i * 16 + arow) * 32 + ak];
#pragma unroll
    for (int j = 0; j < 4; j++)
      bfr[j] = *(const short8*)&Bs[(wn + j * 16 + arow) * 32 + ak];
#pragma unroll
    for (int i = 0; i < 4; i++)
#pragma unroll
      for (int j = 0; j < 4; j++)
        acc[i][j] = __builtin_amdgcn_mfma_f32_16x16x32_bf16(af[i], bfr[j], acc[i][j], 0, 0, 0);
  }

  // D layout: row = quad*4 + reg, col = lane&15 (HW-verified m89/m91)
  const int quad = lane >> 4;
  const int coll = lane & 15;
  float bv[4] = {0.f, 0.f, 0.f, 0.f};
  if (bias) {
#pragma unroll
    for (int j = 0; j < 4; j++) bv[j] = bias[n_base + wn + j * 16 + coll];
  }
#pragma unroll
  for (int i = 0; i < 4; i++) {
#pragma unroll
    for (int r = 0; r < 4; r++) {
      const size_t row = (size_t)(m_base + wm + i * 16 + quad * 4 + r);
#pragma unroll
      for (int j = 0; j < 4; j++) {
        const size_t off = row * (size_t)ldc + (n_base + wn + j * 16 + coll);
        Cout[off] = acc[i][j][r] + bv[j];
      }
    }
  }
}

// H[lm][i] = tanh(Pe[b*256+t][i] + Pd[b*64+u][i] + b1[i]) as bf16,
// global m = m0 + lm, b = m>>14, t = (m>>6)&255, u = m&63. 8 elems/thread.
__global__ __launch_bounds__(256)
void tanh_fuse(const float* __restrict__ Pe, const float* __restrict__ Pd,
               const float* __restrict__ b1, short* __restrict__ H, int m0)
{
  const int idx = blockIdx.x * 256 + threadIdx.x;
  const int lm = idx >> 6;
  const int c = (idx & 63) << 3;
  const int m = m0 + lm;
  const int b = m >> 14;
  const int t = (m >> 6) & 255;
  const int u = m & 63;

  const float* pe = Pe + (size_t)((b << 8) + t) * 512 + c;
  const float* pd = Pd + (size_t)((b << 6) + u) * 512 + c;
  const float4 e0 = *(const float4*)pe;
  const float4 e1 = *(const float4*)(pe + 4);
  const float4 d0 = *(const float4*)pd;
  const float4 d1 = *(const float4*)(pd + 4);
  const float4 g0 = *(const float4*)(b1 + c);
  const float4 g1 = *(const float4*)(b1 + c + 4);

  float x[8] = {e0.x + d0.x + g0.x, e0.y + d0.y + g0.y,
                e0.z + d0.z + g0.z, e0.w + d0.w + g0.w,
                e1.x + d1.x + g1.x, e1.y + d1.y + g1.y,
                e1.z + d1.z + g1.z, e1.w + d1.w + g1.w};
  short8 o;
#pragma unroll
  for (int j = 0; j < 8; j++) {
    const float e  = __expf(2.0f * x[j]);        // inf-safe: tanh -> +/-1
    const float th = 1.0f - 2.0f / (e + 1.0f);
    o[j] = f2bf(th);
  }
  *(short8*)(H + (size_t)lm * 512 + c) = o;
}

extern "C" void kernel_launch(void* const* d_in, const int* in_sizes, int n_in,
                              void* d_out, int out_size, void* d_ws, size_t ws_size,
                              hipStream_t stream)
{
  const float* enc = (const float*)d_in[0];  // (4,256,640)
  const float* dec = (const float*)d_in[1];  // (4,64,640)
  const float* W1  = (const float*)d_in[2];  // (512,1280)
  const float* b1  = (const float*)d_in[3];  // (512,)
  const float* W2  = (const float*)d_in[4];  // (2048,512)
  const float* b2  = (const float*)d_in[5];  // (2048,)
  float* out = (float*)d_out;                // (4,256,64,2048)

  // ws layout (256B aligned): bf16 copies + fp32 projections + chunked H
  size_t off = 0;
  auto carve = [&](size_t bytes) -> void* {
    void* p = (char*)d_ws + off;
    off += (bytes + 255) & ~(size_t)255;
    return p;
  };
  short* encb = (short*)carve(1024 * 640 * 2);   // 1.25 MB
  short* decb = (short*)carve(256 * 640 * 2);    // 0.31 MB
  short* W1b  = (short*)carve(512 * 1280 * 2);   // 1.25 MB
  short* W2b  = (short*)carve(2048 * 512 * 2);   // 2 MB
  float* Pe   = (float*)carve(1024 * 512 * 4);   // 2 MB
  float* Pd   = (float*)carve(256 * 512 * 4);    // 0.5 MB
  short* H    = (short*)((char*)d_ws + off);     // up to 64 MB, chunked

  // H chunk rows: what fits, multiple of 128 (min 128 to guarantee progress)
  const size_t avail = (ws_size > off) ? (ws_size - off) : 0;
  long long rpc = (long long)(avail / (512 * 2));
  rpc = (rpc / 128) * 128;
  if (rpc < 128) rpc = 128;
  if (rpc > 65536) rpc = 65536;

  // fp32 -> bf16 copies (grid computed from n8 — round-2 bug was a hardcoded
  // 32-block grid for dec that covered only 40% of its elements)
  auto cgrid = [](int n8) { return (unsigned)((n8 + 255) / 256); };
  const int n8_enc = 1024 * 640 / 8;   // 81920
  const int n8_dec = 256 * 640 / 8;    // 20480
  const int n8_W1  = 512 * 1280 / 8;   // 81920
  const int n8_W2  = 2048 * 512 / 8;   // 131072
  f32_to_bf16<<<cgrid(n8_enc), 256, 0, stream>>>(enc, encb, n8_enc);
  f32_to_bf16<<<cgrid(n8_dec), 256, 0, stream>>>(dec, decb, n8_dec);
  f32_to_bf16<<<cgrid(n8_W1),  256, 0, stream>>>(W1,  W1b,  n8_W1);
  f32_to_bf16<<<cgrid(n8_W2),  256, 0, stream>>>(W2,  W2b,  n8_W2);

  // enc_proj: M=1024, N=512, K=640 (W1 cols [0,640))
  gemm_bt<<<dim3(4, 8), 256, 0, stream>>>(encb, 640, W1b, 1280, 0,   Pe, 512, nullptr, 640);
  // dec_proj: M=256, N=512, K=640 (W1 cols [640,1280))
  gemm_bt<<<dim3(4, 2), 256, 0, stream>>>(decb, 640, W1b, 1280, 640, Pd, 512, nullptr, 640);

  // chunked: H = tanh(...) then logits = H @ W2^T + b2
  for (long long m0 = 0; m0 < 65536; m0 += rpc) {
    const long long rows = (65536 - m0 < rpc) ? (65536 - m0) : rpc;
    tanh_fuse<<<(unsigned)(rows / 4), 256, 0, stream>>>(Pe, Pd, b1, H, (int)m0);
    gemm_bt<<<dim3(16, (unsigned)(rows / 128)), 256, 0, stream>>>(
        H, 512, W2b, 512, 0, out + (size_t)m0 * 2048, 2048, b2, 512);
  }
}